// Round 3
// baseline (240.440 us; speedup 1.0000x reference)
//
#include <hip/hip_runtime.h>

#define Bdim 32
#define Tdim 256
#define Cdim 1024

typedef unsigned short u16;
typedef unsigned int u32;
typedef __bf16 bf16x8 __attribute__((ext_vector_type(8)));
typedef float f32x4 __attribute__((ext_vector_type(4)));

__device__ __forceinline__ float bf2f(u32 u) {
    union { u32 i; float f; } v; v.i = u << 16; return v.f;
}
__device__ __forceinline__ u16 f2bf(float f) {
    union { float f; u32 i; } v; v.f = f;
    u32 u = v.i;
    return (u16)((u + 0x7fffu + ((u >> 16) & 1u)) >> 16);  // RNE
}

__device__ __forceinline__ void gload16(const u16* g, u16* l) {
    __builtin_amdgcn_global_load_lds(
        (__attribute__((address_space(1))) const void*)g,
        (__attribute__((address_space(3))) void*)l, 16, 0, 0);
}

// ---- fused prep (x mixing -> bf16) + weight convert ---------------------------
__global__ __launch_bounds__(256) void prep_fused(
    const float* __restrict__ x, const float* __restrict__ tmk,
    const float* __restrict__ tmv, const float* __restrict__ tmr,
    u16* __restrict__ xk, u16* __restrict__ xv, u16* __restrict__ xr,
    const float* __restrict__ w0, const float* __restrict__ w1,
    const float* __restrict__ w2, const float* __restrict__ w3,
    u16* __restrict__ o0, u16* __restrict__ o1,
    u16* __restrict__ o2, u16* __restrict__ o3)
{
    int bid = blockIdx.x;
    if (bid < 4096) {
        int tid = bid * 256 + threadIdx.x;
        int e = tid << 3;
        int c = e & (Cdim - 1);
        int t = (e >> 10) & (Tdim - 1);
        float xf[8], xxf[8], mk[8], mv[8], mr[8];
        *(float4*)(xf)     = *(const float4*)(x + e);
        *(float4*)(xf + 4) = *(const float4*)(x + e + 4);
        if (t != 0) {
            *(float4*)(xxf)     = *(const float4*)(x + e - Cdim);
            *(float4*)(xxf + 4) = *(const float4*)(x + e - Cdim + 4);
        } else {
#pragma unroll
            for (int j = 0; j < 8; j++) xxf[j] = 0.f;
        }
        *(float4*)(mk)     = *(const float4*)(tmk + c);
        *(float4*)(mk + 4) = *(const float4*)(tmk + c + 4);
        *(float4*)(mv)     = *(const float4*)(tmv + c);
        *(float4*)(mv + 4) = *(const float4*)(tmv + c + 4);
        *(float4*)(mr)     = *(const float4*)(tmr + c);
        *(float4*)(mr + 4) = *(const float4*)(tmr + c + 4);
        u16 ok[8], ov[8], orr[8];
#pragma unroll
        for (int j = 0; j < 8; j++) {
            float d = xf[j] - xxf[j];
            ok[j]  = f2bf(xxf[j] + d * mk[j]);
            ov[j]  = f2bf(xxf[j] + d * mv[j]);
            orr[j] = f2bf(xxf[j] + d * mr[j]);
        }
        *(uint4*)(xk + e) = *(const uint4*)ok;
        *(uint4*)(xv + e) = *(const uint4*)ov;
        *(uint4*)(xr + e) = *(const uint4*)orr;
    } else {
        int wb = bid - 4096;                 // 0..2047
        int m = wb >> 9;                     // matrix 0..3
        const float* src; u16* dst;
        switch (m) {
            case 0: src = w0; dst = o0; break;
            case 1: src = w1; dst = o1; break;
            case 2: src = w2; dst = o2; break;
            default: src = w3; dst = o3; break;
        }
        int i = (((wb & 511) << 8) + threadIdx.x) << 3;
        float a[8];
        *(float4*)(a)     = *(const float4*)(src + i);
        *(float4*)(a + 4) = *(const float4*)(src + i + 4);
        u16 o[8];
#pragma unroll
        for (int j = 0; j < 8; j++) o[j] = f2bf(a[j]);
        *(uint4*)(dst + i) = *(const uint4*)o;
    }
}

// ---- GEMM body: C[8192,1024] = A[8192,1024] * Bw[1024,1024]^T (bf16 MFMA) -----
// m201-faithful port: 256x256 tile, BK=64, 512 threads = 8 waves (2M x 4N),
// per-wave output 128x64 (acc[8][4]).  4 quadrant-phases per K-tile:
//   ph0: read A0-half(12: 8A+4B with B0) -> MFMA A0xB0
//   ph1: read B1-half(4)                 -> MFMA A0xB1
//   ph2: read A1-half(8, overwrite af)   -> MFMA A1xB1
//   ph3: no reads                        -> MFMA A1xB0
// Staging in 16KB units (2 x global_load_lds), ONE per phase, for tile t+1:
// order A-X, B-X, B-Y, A-Y, where units are defined by CONSUMPTION rows:
//   A-X = global rows {0-63,128-191} (both wm's A0-half) at LDS rows' 0-127
//   A-Y = {64-127,192-255} at rows' 128-255
//   B-X = n rows {0-31,64-95,128-159,192-223} (all wn's B0 cols) at rows' 0-127
//   B-Y = the B1 cols at rows' 128-255
// (legal: gload dest is LDS-contiguous; SOURCE rows are per-lane arbitrary).
// Ledger (induction-verified): every phase ends `vmcnt(4)` + s_barrier, which
// proves exactly the unit consumed 2 phases later; 4 loads always in flight;
// drain 4->2->0 only in the last tile.  (T3+T4+T5; T2 swizzle as in r1/r2:
// element (row,k) at byte (row*128 + 2k) ^ ((row&7)<<4), inverse-swizzled
// global source chunk = (tid&7)^((tid>>3)&7); measured 0 bank conflicts.)
template <int BF16OUT>
__device__ __forceinline__ void gemm_body256(
    const u16* __restrict__ A, const u16* __restrict__ Bw, void* __restrict__ Cout,
    u16* __restrict__ Ls, int bm, int bn)
{
    const int K = Cdim, N = Cdim;
    const int NT = K / 64;                    // 16 K-tiles
    const int tid = threadIdx.x;
    const int lane = tid & 63, wave = tid >> 6;
    const int wm = wave >> 2;                 // 0..1 (M 128-chunk)
    const int wn = wave & 3;                  // 0..3 (N 64-chunk)
    const int fr = lane & 15, quad = lane >> 4;
    const int fr7 = fr & 7;

    // staging source (inverse-swizzled global chunk, linear LDS dest)
    const int srow = tid >> 3;                           // 0..63
    const int schunk = ((tid & 7) ^ (srow & 7)) << 3;    // u16 offset in row
    const u16* gA = A + (size_t)(bm * 256 + srow) * K + schunk;
    const int gbrow = ((srow >> 5) << 6) + (srow & 31);  // B unit-row mapping
    const u16* gB = Bw + (size_t)(bn * 256 + gbrow) * K + schunk;
    u16* lA = Ls + (wave << 9);               // + buf*16384 + cb*4096
    u16* lB = Ls + 32768 + (wave << 9);

    auto stAX = [&](int T, int buf) {
        const u16* g = gA + T * 64;
        u16* l = lA + buf * 16384;
        gload16(g,                   l);
        gload16(g + (size_t)128 * K, l + 4096);
    };
    auto stBX = [&](int T, int buf) {
        const u16* g = gB + T * 64;
        u16* l = lB + buf * 16384;
        gload16(g,                   l);
        gload16(g + (size_t)128 * K, l + 4096);
    };
    auto stBY = [&](int T, int buf) {
        const u16* g = gB + T * 64;
        u16* l = lB + buf * 16384;
        gload16(g + (size_t)32 * K,  l + 8192);
        gload16(g + (size_t)160 * K, l + 12288);
    };
    auto stAY = [&](int T, int buf) {
        const u16* g = gA + T * 64;
        u16* l = lA + buf * 16384;
        gload16(g + (size_t)64 * K,  l + 8192);
        gload16(g + (size_t)192 * K, l + 12288);
    };

    // read bases: A rowgroup i<4 at LDS row' arX+i*16; i>=4 at 128+arX+(i-4)*16
    //             B colgroup j<2 at LDS row' brX+j*16; j>=2 at 128+brX+(j-2)*16
    const int arX = wm * 64 + fr;
    const int brX = wn * 32 + fr;

    f32x4 acc[8][4];
#pragma unroll
    for (int i = 0; i < 8; i++)
#pragma unroll
        for (int j = 0; j < 4; j++)
            acc[i][j] = (f32x4){0.f, 0.f, 0.f, 0.f};

    bf16x8 af[4][2], b0[2][2], b1[2][2];

#define KOFF(s) ((((s << 2) + quad) ^ fr7) << 3)
#define MFMA_Q(I0, J0, BFR)                                                   \
    _Pragma("unroll")                                                         \
    for (int s = 0; s < 2; ++s)                                               \
        _Pragma("unroll")                                                     \
        for (int i = 0; i < 4; ++i)                                           \
            _Pragma("unroll")                                                 \
            for (int j = 0; j < 2; ++j)                                       \
                acc[(I0) + i][(J0) + j] = __builtin_amdgcn_mfma_f32_16x16x32_bf16( \
                    af[i][s], BFR[j][s], acc[(I0) + i][(J0) + j], 0, 0, 0);

    // prologue: stage tile 0's 4 units; prove A-X(0), B-X(0) landed
    stAX(0, 0); stBX(0, 0); stBY(0, 0); stAY(0, 0);
    asm volatile("s_waitcnt vmcnt(4)" ::: "memory");
    __builtin_amdgcn_s_barrier();

#pragma unroll 1
    for (int t = 0; t < NT; ++t) {
        const int buf = t & 1, nb = buf ^ 1;
        const u16* __restrict__ Ab = Ls + buf * 16384;
        const u16* __restrict__ Bb = Ls + 32768 + buf * 16384;
        const bool st = (t + 1 < NT);

        // ---- phase 0: read A0-half + B0-half; stage A-X(t+1); MFMA A0xB0 ----
#pragma unroll
        for (int i = 0; i < 4; ++i)
#pragma unroll
            for (int s = 0; s < 2; ++s)
                af[i][s] = *(const bf16x8*)(Ab + (arX + i * 16) * 64 + KOFF(s));
#pragma unroll
        for (int j = 0; j < 2; ++j)
#pragma unroll
            for (int s = 0; s < 2; ++s)
                b0[j][s] = *(const bf16x8*)(Bb + (brX + j * 16) * 64 + KOFF(s));
        if (st) stAX(t + 1, nb);
        __builtin_amdgcn_s_barrier();
        asm volatile("s_waitcnt lgkmcnt(0)" ::: "memory");
        __builtin_amdgcn_sched_barrier(0);
        __builtin_amdgcn_s_setprio(1);
        MFMA_Q(0, 0, b0)
        __builtin_amdgcn_s_setprio(0);
        if (st) { asm volatile("s_waitcnt vmcnt(4)" ::: "memory"); }
        else    { asm volatile("s_waitcnt vmcnt(2)" ::: "memory"); }
        __builtin_amdgcn_s_barrier();

        // ---- phase 1: read B1-half; stage B-X(t+1); MFMA A0xB1 ----
#pragma unroll
        for (int j = 0; j < 2; ++j)
#pragma unroll
            for (int s = 0; s < 2; ++s)
                b1[j][s] = *(const bf16x8*)(Bb + (128 + brX + j * 16) * 64 + KOFF(s));
        if (st) stBX(t + 1, nb);
        __builtin_amdgcn_s_barrier();
        asm volatile("s_waitcnt lgkmcnt(0)" ::: "memory");
        __builtin_amdgcn_sched_barrier(0);
        __builtin_amdgcn_s_setprio(1);
        MFMA_Q(0, 2, b1)
        __builtin_amdgcn_s_setprio(0);
        if (st) { asm volatile("s_waitcnt vmcnt(4)" ::: "memory"); }
        else    { asm volatile("s_waitcnt vmcnt(0)" ::: "memory"); }
        __builtin_amdgcn_s_barrier();

        // ---- phase 2: read A1-half (overwrite af); stage B-Y(t+1); MFMA A1xB1 ----
#pragma unroll
        for (int i = 0; i < 4; ++i)
#pragma unroll
            for (int s = 0; s < 2; ++s)
                af[i][s] = *(const bf16x8*)(Ab + (128 + arX + i * 16) * 64 + KOFF(s));
        if (st) stBY(t + 1, nb);
        __builtin_amdgcn_s_barrier();
        asm volatile("s_waitcnt lgkmcnt(0)" ::: "memory");
        __builtin_amdgcn_sched_barrier(0);
        __builtin_amdgcn_s_setprio(1);
        MFMA_Q(4, 2, b1)
        __builtin_amdgcn_s_setprio(0);
        if (st) { asm volatile("s_waitcnt vmcnt(4)" ::: "memory"); }
        __builtin_amdgcn_s_barrier();

        // ---- phase 3: no reads; stage A-Y(t+1); MFMA A1xB0 ----
        if (st) stAY(t + 1, nb);
        __builtin_amdgcn_s_barrier();
        __builtin_amdgcn_s_setprio(1);
        MFMA_Q(4, 0, b0)
        __builtin_amdgcn_s_setprio(0);
        if (st) { asm volatile("s_waitcnt vmcnt(4)" ::: "memory"); }
        __builtin_amdgcn_s_barrier();
    }
#undef MFMA_Q
#undef KOFF

    // C/D layout: row = quad*4 + reg, col = lane&15  [m89-verified]
    const int gr0 = bm * 256 + wm * 128 + quad * 4;
    const int gc0 = bn * 256 + wn * 64 + fr;
#pragma unroll
    for (int i = 0; i < 8; i++)
#pragma unroll
        for (int j = 0; j < 4; j++)
#pragma unroll
            for (int r = 0; r < 4; r++) {
                int gr = gr0 + i * 16 + r;
                int gc = gc0 + j * 16;
                float val = acc[i][j][r];
                if (BF16OUT)
                    ((u16*)Cout)[(size_t)gr * N + gc] = f2bf(val);
                else
                    ((float*)Cout)[(size_t)gr * N + gc] = val;
            }
}

// grouped GEMM for k/v/r (blockIdx.z selects operand set), bf16 out
// XCD locality: bm = bx&31 -> blocks sharing an A row-panel satisfy
// bx%8 = bm%8 (same XCD); z overlays the same mapping.
__global__ __launch_bounds__(512, 2) void gemm3_kernel(
    const u16* __restrict__ xk, const u16* __restrict__ xv, const u16* __restrict__ xr,
    const u16* __restrict__ wk, const u16* __restrict__ wv, const u16* __restrict__ wr,
    u16* __restrict__ ck, u16* __restrict__ cv, u16* __restrict__ cr)
{
    __shared__ __align__(16) u16 Ls[4 * 16384];   // 128 KiB: A dbuf + B dbuf
    const u16* A; const u16* Bw; u16* Cout;
    switch (blockIdx.z) {
        case 0:  A = xk; Bw = wk; Cout = ck; break;
        case 1:  A = xv; Bw = wv; Cout = cv; break;
        default: A = xr; Bw = wr; Cout = cr; break;
    }
    int bx = blockIdx.x;
    gemm_body256<1>(A, Bw, (void*)Cout, Ls, bx & 31, bx >> 5);
}

// final GEMM, f32 out
__global__ __launch_bounds__(512, 2) void gemmo_kernel(
    const u16* __restrict__ A, const u16* __restrict__ Bw, float* __restrict__ Cout)
{
    __shared__ __align__(16) u16 Ls[4 * 16384];
    int bx = blockIdx.x;
    gemm_body256<0>(A, Bw, (void*)Cout, Ls, bx & 31, bx >> 5);
}

// ---- WKV scan + sigmoid(r) gate; register double-buffered prefetch ------------
#define WTC 16

#define LOADCHUNK(KA, VA, RA, T0)                                        \
    _Pragma("unroll")                                                    \
    for (int s = 0; s < WTC; s++) {                                      \
        size_t idx = base + (size_t)((T0) + s) * Cdim;                   \
        KA[s] = kb[idx]; VA[s] = vb[idx]; RA[s] = rb[idx];               \
    }

#define COMPCHUNK(KA, VA, RA, T0)                                        \
    _Pragma("unroll")                                                    \
    for (int s = 0; s < WTC; s++) {                                      \
        float kt = bf2f(KA[s]);                                          \
        float vt = bf2f(VA[s]);                                          \
        float rt = bf2f(RA[s]);                                          \
        float uk = u + kt;                                               \
        float no = fmaxf(o, uk);                                         \
        float Ae = __expf(o - no);                                       \
        float Bc = __expf(uk - no);                                      \
        float num = Ae * p + Bc * vt;                                    \
        float den = Ae * q + Bc;                                         \
        float y = num * __builtin_amdgcn_rcpf(den);                      \
        float sr = __builtin_amdgcn_rcpf(1.f + __expf(-rt));             \
        rwkv[base + (size_t)((T0) + s) * Cdim] = f2bf(y * sr);           \
        float wo = w + o;                                                \
        float no2 = fmaxf(wo, kt);                                       \
        float A2 = __expf(wo - no2);                                     \
        float B2 = __expf(kt - no2);                                     \
        p = A2 * p + B2 * vt;                                            \
        q = A2 * q + B2;                                                 \
        o = no2;                                                         \
    }

__global__ __launch_bounds__(64) void wkv_kernel(
    const u16* __restrict__ kb, const u16* __restrict__ vb,
    const u16* __restrict__ rb, const float* __restrict__ td,
    const float* __restrict__ tfirst, u16* __restrict__ rwkv)
{
    int lane = threadIdx.x;
    int blk = blockIdx.x;            // 512 blocks
    int b = blk >> 4;
    int c = ((blk & 15) << 6) + lane;
    float w = -__expf(td[c]);
    float u = tfirst[c];
    const size_t base = (size_t)b * Tdim * Cdim + c;

    u32 kA[WTC], vA[WTC], rA[WTC];
    u32 kB[WTC], vB[WTC], rB[WTC];
    float p = 0.f, q = 0.f, o = -1e38f;

    LOADCHUNK(kA, vA, rA, 0)
    for (int t0 = 0; t0 < Tdim; t0 += 2 * WTC) {
        LOADCHUNK(kB, vB, rB, t0 + WTC)
        COMPCHUNK(kA, vA, rA, t0)
        if (t0 + 2 * WTC < Tdim) {
            LOADCHUNK(kA, vA, rA, t0 + 2 * WTC)
        }
        COMPCHUNK(kB, vB, rB, t0 + WTC)
    }
}

extern "C" void kernel_launch(void* const* d_in, const int* in_sizes, int n_in,
                              void* d_out, int out_size, void* d_ws, size_t ws_size,
                              hipStream_t stream) {
    (void)in_sizes; (void)n_in; (void)out_size; (void)ws_size;
    const float* x   = (const float*)d_in[0];
    const float* td  = (const float*)d_in[1];
    const float* tfi = (const float*)d_in[2];
    const float* tmk = (const float*)d_in[3];
    const float* tmv = (const float*)d_in[4];
    const float* tmr = (const float*)d_in[5];
    const float* Wk  = (const float*)d_in[6];
    const float* Wv  = (const float*)d_in[7];
    const float* Wr  = (const float*)d_in[8];
    const float* Wo  = (const float*)d_in[9];

    char* ws = (char*)d_ws;
    const size_t MiB = (size_t)1 << 20;
    u16* xk    = (u16*)(ws);             // [0,16)
    u16* xv    = (u16*)(ws + 16 * MiB);  // [16,32)
    u16* xr    = (u16*)(ws + 32 * MiB);  // [32,48)
    u16* wkb   = (u16*)(ws + 48 * MiB);  // [48,50)
    u16* wvb   = (u16*)(ws + 50 * MiB);  // [50,52)
    u16* wrb   = (u16*)(ws + 52 * MiB);  // [52,54)
    u16* wob   = (u16*)(ws + 54 * MiB);  // [54,56)
    u16* kb    = (u16*)(ws + 56 * MiB);  // [56,72)
    u16* vb    = (u16*)(ws + 72 * MiB);  // [72,88)
    u16* rb    = (u16*)(ws + 88 * MiB);  // [88,104) — no alias: gemm3 z's run concurrently
    u16* rwkvb = (u16*)(ws);             // [0,16) — overlaps xk (dead after gemm3)

    prep_fused<<<6144, 256, 0, stream>>>(x, tmk, tmv, tmr, xk, xv, xr,
                                         Wk, Wv, Wr, Wo, wkb, wvb, wrb, wob);

    gemm3_kernel<<<dim3(128, 1, 3), 512, 0, stream>>>(xk, xv, xr, wkb, wvb, wrb,
                                                      kb, vb, rb);

    wkv_kernel<<<512, 64, 0, stream>>>(kb, vb, rb, td, tfi, rwkvb);

    gemmo_kernel<<<128, 512, 0, stream>>>(rwkvb, wob, (float*)d_out);
}

// Round 4
// 226.904 us; speedup vs baseline: 1.0597x; 1.0597x over previous
//
#include <hip/hip_runtime.h>

#define Bdim 32
#define Tdim 256
#define Cdim 1024

typedef unsigned short u16;
typedef unsigned int u32;
typedef __bf16 bf16x8 __attribute__((ext_vector_type(8)));
typedef float f32x4 __attribute__((ext_vector_type(4)));

__device__ __forceinline__ float bf2f(u32 u) {
    union { u32 i; float f; } v; v.i = u << 16; return v.f;
}
__device__ __forceinline__ u16 f2bf(float f) {
    union { float f; u32 i; } v; v.f = f;
    u32 u = v.i;
    return (u16)((u + 0x7fffu + ((u >> 16) & 1u)) >> 16);  // RNE
}

__device__ __forceinline__ void gload16(const u16* g, u16* l) {
    __builtin_amdgcn_global_load_lds(
        (__attribute__((address_space(1))) const void*)g,
        (__attribute__((address_space(3))) void*)l, 16, 0, 0);
}

// ---- fused prep (x mixing -> bf16) + weight convert ---------------------------
__global__ __launch_bounds__(256) void prep_fused(
    const float* __restrict__ x, const float* __restrict__ tmk,
    const float* __restrict__ tmv, const float* __restrict__ tmr,
    u16* __restrict__ xk, u16* __restrict__ xv, u16* __restrict__ xr,
    const float* __restrict__ w0, const float* __restrict__ w1,
    const float* __restrict__ w2, const float* __restrict__ w3,
    u16* __restrict__ o0, u16* __restrict__ o1,
    u16* __restrict__ o2, u16* __restrict__ o3)
{
    int bid = blockIdx.x;
    if (bid < 4096) {
        int tid = bid * 256 + threadIdx.x;
        int e = tid << 3;
        int c = e & (Cdim - 1);
        int t = (e >> 10) & (Tdim - 1);
        float xf[8], xxf[8], mk[8], mv[8], mr[8];
        *(float4*)(xf)     = *(const float4*)(x + e);
        *(float4*)(xf + 4) = *(const float4*)(x + e + 4);
        if (t != 0) {
            *(float4*)(xxf)     = *(const float4*)(x + e - Cdim);
            *(float4*)(xxf + 4) = *(const float4*)(x + e - Cdim + 4);
        } else {
#pragma unroll
            for (int j = 0; j < 8; j++) xxf[j] = 0.f;
        }
        *(float4*)(mk)     = *(const float4*)(tmk + c);
        *(float4*)(mk + 4) = *(const float4*)(tmk + c + 4);
        *(float4*)(mv)     = *(const float4*)(tmv + c);
        *(float4*)(mv + 4) = *(const float4*)(tmv + c + 4);
        *(float4*)(mr)     = *(const float4*)(tmr + c);
        *(float4*)(mr + 4) = *(const float4*)(tmr + c + 4);
        u16 ok[8], ov[8], orr[8];
#pragma unroll
        for (int j = 0; j < 8; j++) {
            float d = xf[j] - xxf[j];
            ok[j]  = f2bf(xxf[j] + d * mk[j]);
            ov[j]  = f2bf(xxf[j] + d * mv[j]);
            orr[j] = f2bf(xxf[j] + d * mr[j]);
        }
        *(uint4*)(xk + e) = *(const uint4*)ok;
        *(uint4*)(xv + e) = *(const uint4*)ov;
        *(uint4*)(xr + e) = *(const uint4*)orr;
    } else {
        int wb = bid - 4096;                 // 0..2047
        int m = wb >> 9;                     // matrix 0..3
        const float* src; u16* dst;
        switch (m) {
            case 0: src = w0; dst = o0; break;
            case 1: src = w1; dst = o1; break;
            case 2: src = w2; dst = o2; break;
            default: src = w3; dst = o3; break;
        }
        int i = (((wb & 511) << 8) + threadIdx.x) << 3;
        float a[8];
        *(float4*)(a)     = *(const float4*)(src + i);
        *(float4*)(a + 4) = *(const float4*)(src + i + 4);
        u16 o[8];
#pragma unroll
        for (int j = 0; j < 8; j++) o[j] = f2bf(a[j]);
        *(uint4*)(dst + i) = *(const uint4*)o;
    }
}

// ---- GEMM body: C[8192,1024] = A[8192,1024] * Bw[1024,1024]^T (bf16 MFMA) -----
// Round-0 structure (128x128 tile, BK=64, 4 waves, rotation swizzle — all
// verified, 0 bank conflicts) + ONE change: double-buffered LDS with
// one-tile-ahead prefetch.  Tile t's loop body: issue the 8 global_load_lds
// for tile t+1 into buffer buf^1, compute tile t from buffer buf, then a
// single vmcnt(0)+lgkmcnt(0)+s_barrier.  Load latency (~200-300cy L2-warm)
// hides under the ~600cy of ds_read+MFMA instead of being exposed at the
// top of each K-tile (the m97-structure's documented ~20% stall).
// Hazard ledger: end-of-(t-1) barrier drains lgkm, so every wave's reads of
// buffer nb are COMPLETE before any wave stages tile t+1 into nb.  LDS =
// 2 x 32 KiB = 64 KiB -> still 2 blocks/CU (r0's measured residency kept).
//
// ROTATION SWIZZLE (unchanged from r0): LDS slot (row,pos) holds k-chunk
// (pos + ((row>>1)&3))&3. Writer thread t (row=t>>2,pos=t&3) fetches global
// chunk ((t&3)+((t>>3)&3))&3; reader lane (fr,quad) reads
// pos=(quad-((fr>>1)&3))&3 — conflict-free (measured 0).
template <int BF16OUT>
__device__ __forceinline__ void gemm_body(
    const u16* __restrict__ A, const u16* __restrict__ Bw, void* __restrict__ Cout,
    u16* __restrict__ Ls, int bm, int bn)
{
    const int K = Cdim, N = Cdim;
    const int NT = K / 64;                   // 16 K-tiles
    const int tid = threadIdx.x;
    const int lane = tid & 63, wave = tid >> 6;
    const int wm = (wave & 1) << 6, wn = (wave >> 1) << 6;
    const int fr = lane & 15, quad = lane >> 4;

    const int srow = tid >> 2;
    const int skc = ((((tid & 3) + ((tid >> 3) & 3)) & 3) << 3);  // rotated chunk
    const u16* ga = A + (size_t)(bm * 128 + srow) * K + skc;
    const u16* gb = Bw + (size_t)(bn * 128 + srow) * K + skc;
    const size_t gstep = (size_t)64 * K;
    const int lw = wave << 9;                // wave-uniform LDS base (u16)

    // buffer layout (u16 offsets within Ls):
    //   buf*16384 + { As0:0, Bs0:4096, As1:8192, Bs1:12288 } + lw + lane*8(HW)
    auto stage = [&](int t, int buf) {
        const u16* gat = ga + t * 64;
        const u16* gbt = gb + t * 64;
        u16* base = Ls + buf * 16384 + lw;
        gload16(gat,              base);
        gload16(gat + gstep,      base + 2048);
        gload16(gbt,              base + 4096);
        gload16(gbt + gstep,      base + 4096 + 2048);
        gload16(gat + 32,         base + 8192);
        gload16(gat + 32 + gstep, base + 8192 + 2048);
        gload16(gbt + 32,         base + 12288);
        gload16(gbt + 32 + gstep, base + 12288 + 2048);
    };

    f32x4 acc[4][4];
#pragma unroll
    for (int i = 0; i < 4; i++)
#pragma unroll
        for (int j = 0; j < 4; j++)
            acc[i][j] = (f32x4){0.f, 0.f, 0.f, 0.f};

    const int rq = (((quad - ((fr >> 1) & 3)) & 3) << 3);  // reader pos (u16)

    // prologue: stage tile 0, drain, barrier
    stage(0, 0);
    asm volatile("s_waitcnt vmcnt(0)" ::: "memory");
    __builtin_amdgcn_s_barrier();

#pragma unroll 1
    for (int t = 0; t < NT; ++t) {
        const int buf = t & 1;
        if (t + 1 < NT) stage(t + 1, buf ^ 1);   // prefetch next tile
        const u16* __restrict__ Tb = Ls + buf * 16384;
#pragma unroll
        for (int h = 0; h < 2; h++) {
            const u16* Ah = Tb + h * 8192;
            const u16* Bh = Tb + 4096 + h * 8192;
            bf16x8 af[4], bfr[4];
#pragma unroll
            for (int i = 0; i < 4; i++) {
                af[i]  = *(const bf16x8*)(Ah + (wm + i * 16 + fr) * 32 + rq);
                bfr[i] = *(const bf16x8*)(Bh + (wn + i * 16 + fr) * 32 + rq);
            }
#pragma unroll
            for (int i = 0; i < 4; i++)
#pragma unroll
                for (int j = 0; j < 4; j++)
                    acc[i][j] = __builtin_amdgcn_mfma_f32_16x16x32_bf16(
                        af[i], bfr[j], acc[i][j], 0, 0, 0);
        }
        // next tile's loads landed during compute; short drain, one barrier
        asm volatile("s_waitcnt vmcnt(0) lgkmcnt(0)" ::: "memory");
        __builtin_amdgcn_s_barrier();
    }

    // C/D layout: row = quad*4 + reg, col = lane&15  [m89-verified]
    const int gr0 = bm * 128 + wm + quad * 4;
    const int gc0 = bn * 128 + wn + fr;
#pragma unroll
    for (int i = 0; i < 4; i++)
#pragma unroll
        for (int j = 0; j < 4; j++)
#pragma unroll
            for (int r = 0; r < 4; r++) {
                int gr = gr0 + i * 16 + r;
                int gc = gc0 + j * 16;
                float val = acc[i][j][r];
                if (BF16OUT)
                    ((u16*)Cout)[(size_t)gr * N + gc] = f2bf(val);
                else
                    ((float*)Cout)[(size_t)gr * N + gc] = val;
            }
}

// grouped GEMM for k/v/r (blockIdx.z selects operand set), bf16 out
// XCD swizzle: bm = x&63 -> XCD = x%8 = bm%8, so all 8 bn-blocks sharing an
// A row-block co-reside on one XCD (per-XCD L2 working set fits).
__global__ __launch_bounds__(256) void gemm3_kernel(
    const u16* __restrict__ xk, const u16* __restrict__ xv, const u16* __restrict__ xr,
    const u16* __restrict__ wk, const u16* __restrict__ wv, const u16* __restrict__ wr,
    u16* __restrict__ ck, u16* __restrict__ cv, u16* __restrict__ cr)
{
    __shared__ __align__(16) u16 Ls[2 * 16384];   // 64 KiB double buffer
    const u16* A; const u16* Bw; u16* Cout;
    switch (blockIdx.z) {
        case 0:  A = xk; Bw = wk; Cout = ck; break;
        case 1:  A = xv; Bw = wv; Cout = cv; break;
        default: A = xr; Bw = wr; Cout = cr; break;
    }
    int bx = blockIdx.x;
    gemm_body<1>(A, Bw, (void*)Cout, Ls, bx & 63, bx >> 6);
}

// final GEMM, f32 out
__global__ __launch_bounds__(256) void gemmo_kernel(
    const u16* __restrict__ A, const u16* __restrict__ Bw, float* __restrict__ Cout)
{
    __shared__ __align__(16) u16 Ls[2 * 16384];
    int bx = blockIdx.x;
    gemm_body<0>(A, Bw, (void*)Cout, Ls, bx & 63, bx >> 6);
}

// ---- WKV scan + sigmoid(r) gate; register double-buffered prefetch ------------
#define WTC 16

#define LOADCHUNK(KA, VA, RA, T0)                                        \
    _Pragma("unroll")                                                    \
    for (int s = 0; s < WTC; s++) {                                      \
        size_t idx = base + (size_t)((T0) + s) * Cdim;                   \
        KA[s] = kb[idx]; VA[s] = vb[idx]; RA[s] = rb[idx];               \
    }

#define COMPCHUNK(KA, VA, RA, T0)                                        \
    _Pragma("unroll")                                                    \
    for (int s = 0; s < WTC; s++) {                                      \
        float kt = bf2f(KA[s]);                                          \
        float vt = bf2f(VA[s]);                                          \
        float rt = bf2f(RA[s]);                                          \
        float uk = u + kt;                                               \
        float no = fmaxf(o, uk);                                         \
        float Ae = __expf(o - no);                                       \
        float Bc = __expf(uk - no);                                      \
        float num = Ae * p + Bc * vt;                                    \
        float den = Ae * q + Bc;                                         \
        float y = num * __builtin_amdgcn_rcpf(den);                      \
        float sr = __builtin_amdgcn_rcpf(1.f + __expf(-rt));             \
        rwkv[base + (size_t)((T0) + s) * Cdim] = f2bf(y * sr);           \
        float wo = w + o;                                                \
        float no2 = fmaxf(wo, kt);                                       \
        float A2 = __expf(wo - no2);                                     \
        float B2 = __expf(kt - no2);                                     \
        p = A2 * p + B2 * vt;                                            \
        q = A2 * q + B2;                                                 \
        o = no2;                                                         \
    }

__global__ __launch_bounds__(64) void wkv_kernel(
    const u16* __restrict__ kb, const u16* __restrict__ vb,
    const u16* __restrict__ rb, const float* __restrict__ td,
    const float* __restrict__ tfirst, u16* __restrict__ rwkv)
{
    int lane = threadIdx.x;
    int blk = blockIdx.x;            // 512 blocks
    int b = blk >> 4;
    int c = ((blk & 15) << 6) + lane;
    float w = -__expf(td[c]);
    float u = tfirst[c];
    const size_t base = (size_t)b * Tdim * Cdim + c;

    u32 kA[WTC], vA[WTC], rA[WTC];
    u32 kB[WTC], vB[WTC], rB[WTC];
    float p = 0.f, q = 0.f, o = -1e38f;

    LOADCHUNK(kA, vA, rA, 0)
    for (int t0 = 0; t0 < Tdim; t0 += 2 * WTC) {
        LOADCHUNK(kB, vB, rB, t0 + WTC)
        COMPCHUNK(kA, vA, rA, t0)
        if (t0 + 2 * WTC < Tdim) {
            LOADCHUNK(kA, vA, rA, t0 + 2 * WTC)
        }
        COMPCHUNK(kB, vB, rB, t0 + WTC)
    }
}

extern "C" void kernel_launch(void* const* d_in, const int* in_sizes, int n_in,
                              void* d_out, int out_size, void* d_ws, size_t ws_size,
                              hipStream_t stream) {
    (void)in_sizes; (void)n_in; (void)out_size; (void)ws_size;
    const float* x   = (const float*)d_in[0];
    const float* td  = (const float*)d_in[1];
    const float* tfi = (const float*)d_in[2];
    const float* tmk = (const float*)d_in[3];
    const float* tmv = (const float*)d_in[4];
    const float* tmr = (const float*)d_in[5];
    const float* Wk  = (const float*)d_in[6];
    const float* Wv  = (const float*)d_in[7];
    const float* Wr  = (const float*)d_in[8];
    const float* Wo  = (const float*)d_in[9];

    char* ws = (char*)d_ws;
    const size_t MiB = (size_t)1 << 20;
    u16* xk    = (u16*)(ws);             // [0,16)
    u16* xv    = (u16*)(ws + 16 * MiB);  // [16,32)
    u16* xr    = (u16*)(ws + 32 * MiB);  // [32,48)
    u16* wkb   = (u16*)(ws + 48 * MiB);  // [48,50)
    u16* wvb   = (u16*)(ws + 50 * MiB);  // [50,52)
    u16* wrb   = (u16*)(ws + 52 * MiB);  // [52,54)
    u16* wob   = (u16*)(ws + 54 * MiB);  // [54,56)
    u16* kb    = (u16*)(ws + 56 * MiB);  // [56,72)
    u16* vb    = (u16*)(ws + 72 * MiB);  // [72,88)
    u16* rb    = (u16*)(ws + 88 * MiB);  // [88,104) — no alias: gemm3 z's run concurrently
    u16* rwkvb = (u16*)(ws);             // [0,16) — overlaps xk (dead after gemm3)

    prep_fused<<<6144, 256, 0, stream>>>(x, tmk, tmv, tmr, xk, xv, xr,
                                         Wk, Wv, Wr, Wo, wkb, wvb, wrb, wob);

    gemm3_kernel<<<dim3(512, 1, 3), 256, 0, stream>>>(xk, xv, xr, wkb, wvb, wrb,
                                                      kb, vb, rb);

    wkv_kernel<<<512, 64, 0, stream>>>(kb, vb, rb, td, tfi, rwkvb);

    gemmo_kernel<<<512, 256, 0, stream>>>(rwkvb, wob, (float*)d_out);
}